// Round 11
// baseline (265.150 us; speedup 1.0000x reference)
//
#include <hip/hip_runtime.h>
#include <hip/hip_cooperative_groups.h>
#include <math.h>

namespace cg = cooperative_groups;

#define NB 4096
#define NC 128
#define NK 32
#define NE 128

typedef __bf16 bf16x8 __attribute__((ext_vector_type(8)));
typedef float floatx4 __attribute__((ext_vector_type(4)));

__device__ __forceinline__ float sigmoidf_(float x){
  if (x >= 0.f){ float z = expf(-x); return 1.f/(1.f+z); }
  float z = expf(x); return z/(1.f+z);
}
__device__ __forceinline__ float softplusf_(float x){
  return fmaxf(x, 0.f) + log1pf(expf(-fabsf(x)));
}
__device__ __forceinline__ unsigned int pack_bf16(float a, float b){
  unsigned short ua = __builtin_bit_cast(unsigned short, (__bf16)a);
  unsigned short ub = __builtin_bit_cast(unsigned short, (__bf16)b);
  return (unsigned int)ua | ((unsigned int)ub << 16);
}

struct KParams {
  const float *emb, *gen, *cons, *pos;
  const float *fp_w1, *fp_b1, *fp_w2, *fp_b2, *fp_w3, *fp_b3;
  const float *en_w1, *en_b1, *en_w2, *en_b2;
  const float *ps_w1, *ps_b1, *ps_w2, *ps_b2;
  const int *assign, *hourp;
  float *w1at, *w1bt, *ps_w1t;
  int *g, *row_of;
  float *w1d_c, *bzc;
  uint4 *w2f;
  float *net_c, *prio_c, *pos_c;
  float *hi_c, *hj_c, *pflow, *fl_c, *ef_c;
  float *sharing, *effm, *total, *esent, *erecv, *nafter;
};

// ================== PATH A: single cooperative kernel ==================
// __launch_bounds__(256, 3): arch-VGPR cap ~168 — R8's (256,4) cap of 64 spilled
// catastrophically; R10's (256,2) let VGPR+AGPR exceed 256/wave -> 1 block/CU ->
// cooperative launch of 512 blocks was rejected (all-zero output). 168+AGPRs fits
// 2 waves/SIMD, so 512 blocks co-reside. kernel_launch verifies via occupancy query.
__global__ __launch_bounds__(256, 3) void k_fused(KParams p){
  __shared__ __align__(16) char smem_raw[33536];
  cg::grid_group grid = cg::this_grid();
  int t = threadIdx.x;
  int bid = blockIdx.x;
  int lane = t & 63, wv = t >> 6;

  // ---- P0: prep (verified R8) ----
  if (bid < 80){
    int idx = bid*256 + t;
    if (idx < 128*128){
      int o = idx >> 7, e = idx & 127;
      p.w1at[e*128 + o] = p.fp_w1[o*258 + e];
      p.w1bt[e*128 + o] = p.fp_w1[o*258 + 128 + e];
    } else {
      int i2 = idx - 128*128;
      if (i2 < 128*32){
        int e = i2 >> 5, q = i2 & 31;
        p.ps_w1t[e*32 + q] = p.ps_w1[q*128 + e];
      }
    }
  } else if (bid < 96){
    int* hist = (int*)smem_raw;
    int* loc  = hist + NC;
    int start = (bid - 80)*256;
    for (int c = t; c < NC; c += 256) hist[c] = 0;
    __syncthreads();
    for (int j = t; j < start; j += 256) atomicAdd(&hist[p.assign[j]], 1);
    int i = start + t;
    int c = p.assign[i];
    loc[t] = c;
    __syncthreads();
    int r = hist[c];
    for (int j = 0; j < 256; ++j) r += (j < t && loc[j] == c) ? 1 : 0;
    if (r >= NK) r = NK - 1;
    p.g[c*NK + r] = i;
    p.row_of[i] = c*NK + r;
  } else if (bid == 96){
    if (t < 128){
      float hour_f = (float)p.hourp[0] / 24.0f;
      p.w1d_c[t] = p.fp_w1[t*258 + 256];
      p.bzc[t]   = fmaf(hour_f, p.fp_w1[t*258 + 257], p.fp_b1[t]);
    }
    if (t == 128) p.total[0] = 0.f;
  } else if (bid == 97){
    for (int ff = t; ff < 1024; ff += 256){
      int ln = ff & 63, fi = ff >> 6;
      int nt = fi >> 2, ks = fi & 3;
      int o = nt*16 + (ln & 15);
      int kb = ks*32 + (ln >> 4)*8;
      const float* src = p.fp_w2 + o*128 + kb;
      uint4 u;
      u.x = pack_bf16(src[0], src[1]);
      u.y = pack_bf16(src[2], src[3]);
      u.z = pack_bf16(src[4], src[5]);
      u.w = pack_bf16(src[6], src[7]);
      p.w2f[ff] = u;
    }
  }
  __threadfence();
  grid.sync();

  // ---- P1: merged hij + prio (verified R9) ----
  {
    float* es  = (float*)smem_raw;
    float* wsm = es + 8*132;
    int i0 = bid*8;
    for (int idx = t; idx < 8*128; idx += 256){
      int b = idx >> 7, e = idx & 127;
      es[b*132 + e] = p.emb[(i0 + b)*128 + e];
    }
    for (int idx = t; idx < 128*32; idx += 256) wsm[idx] = p.ps_w1t[idx];
    __syncthreads();
    {
      int o = t & 127, half = t >> 7;
      float ai[4], aj[4];
#pragma unroll
      for (int r = 0; r < 4; ++r){ ai[r] = 0.f; aj[r] = 0.f; }
      for (int e = 0; e < 128; e += 4){
        float wa0 = p.w1at[(e+0)*128 + o], wa1 = p.w1at[(e+1)*128 + o];
        float wa2 = p.w1at[(e+2)*128 + o], wa3 = p.w1at[(e+3)*128 + o];
        float wb0 = p.w1bt[(e+0)*128 + o], wb1 = p.w1bt[(e+1)*128 + o];
        float wb2 = p.w1bt[(e+2)*128 + o], wb3 = p.w1bt[(e+3)*128 + o];
#pragma unroll
        for (int r = 0; r < 4; ++r){
          float4 ev = *(const float4*)&es[(half*4 + r)*132 + e];
          ai[r] = fmaf(ev.x, wa0, fmaf(ev.y, wa1, fmaf(ev.z, wa2, fmaf(ev.w, wa3, ai[r]))));
          aj[r] = fmaf(ev.x, wb0, fmaf(ev.y, wb1, fmaf(ev.z, wb2, fmaf(ev.w, wb3, aj[r]))));
        }
      }
#pragma unroll
      for (int r = 0; r < 4; ++r){
        int b = i0 + half*4 + r;
        int ck = p.row_of[b];
        p.hi_c[ck*128 + o] = ai[r];
        p.hj_c[ck*128 + o] = aj[r];
      }
    }
    {
      int bl = t >> 5, q = t & 31;
      int i = i0 + bl;
      float acc = p.ps_b1[q];
      const float* er = &es[bl*132];
      for (int e = 0; e < 128; ++e) acc = fmaf(er[e], wsm[e*32 + q], acc);
      float v = fmaxf(acc, 0.f) * p.ps_w2[q];
      for (int m = 16; m >= 1; m >>= 1) v += __shfl_xor(v, m, 32);
      if (q == 0){
        int ck = p.row_of[i];
        p.prio_c[ck] = sigmoidf_(v + p.ps_b2[0]);
        int h = p.hourp[0];
        p.net_c[ck] = p.gen[i*24 + h] - p.cons[i*24 + h];
        p.pos_c[2*ck]   = p.pos[2*i];
        p.pos_c[2*ck+1] = p.pos[2*i+1];
      }
    }
  }
  __threadfence();
  grid.sync();

  // ---- P2: pflow via MFMA (verified R6/R8 math) ----
  {
    int l16 = lane & 15, quad = lane >> 4;
    bf16x8 bfr[4][4];
#pragma unroll
    for (int nt = 0; nt < 4; ++nt)
#pragma unroll
      for (int ks = 0; ks < 4; ++ks)
        bfr[nt][ks] = __builtin_bit_cast(bf16x8, p.w2f[(nt*4 + ks)*64 + lane]);
    float b2v[4], w3v[4];
#pragma unroll
    for (int nt = 0; nt < 4; ++nt){
      b2v[nt] = p.fp_b2[nt*16 + l16];
      w3v[nt] = p.fp_w3[nt*16 + l16];
    }
    float b3 = p.fp_b3[0];
    for (int it = 0; it < 4; ++it){
      int gw = it*2048 + bid*4 + wv;
      int c = gw >> 6;
      int rem = gw & 63;
      int i = rem >> 1, j0 = (rem & 1)*16;
      int j = j0 + l16;
      float xi = p.pos_c[(c*NK + i)*2 + 0], yi = p.pos_c[(c*NK + i)*2 + 1];
      float xj = p.pos_c[(c*NK + j)*2 + 0], yj = p.pos_c[(c*NK + j)*2 + 1];
      float dx = xi - xj, dy = yi - yj;
      float d = sqrtf(fmaf(dx, dx, dy*dy));
      const float4* hi4 = (const float4*)(p.hi_c + (c*NK + i)*128);
      const float4* hj4 = (const float4*)(p.hj_c + (c*NK + j)*128);
      const float4* wd4 = (const float4*)p.w1d_c;
      const float4* bz4 = (const float4*)p.bzc;
      bf16x8 af[4];
#pragma unroll
      for (int ks = 0; ks < 4; ++ks){
        int q8 = ks*8 + quad*2;
        float4 a0 = hi4[q8], a1 = hi4[q8 + 1];
        float4 b0 = hj4[q8], b1 = hj4[q8 + 1];
        float4 w0 = wd4[q8], w1 = wd4[q8 + 1];
        float4 z0 = bz4[q8], z1 = bz4[q8 + 1];
        float v0 = fmaxf(a0.x + b0.x + fmaf(d, w0.x, z0.x), 0.f);
        float v1 = fmaxf(a0.y + b0.y + fmaf(d, w0.y, z0.y), 0.f);
        float v2 = fmaxf(a0.z + b0.z + fmaf(d, w0.z, z0.z), 0.f);
        float v3 = fmaxf(a0.w + b0.w + fmaf(d, w0.w, z0.w), 0.f);
        float v4 = fmaxf(a1.x + b1.x + fmaf(d, w1.x, z1.x), 0.f);
        float v5 = fmaxf(a1.y + b1.y + fmaf(d, w1.y, z1.y), 0.f);
        float v6 = fmaxf(a1.z + b1.z + fmaf(d, w1.z, z1.z), 0.f);
        float v7 = fmaxf(a1.w + b1.w + fmaf(d, w1.w, z1.w), 0.f);
        uint4 u;
        u.x = pack_bf16(v0, v1);
        u.y = pack_bf16(v2, v3);
        u.z = pack_bf16(v4, v5);
        u.w = pack_bf16(v6, v7);
        af[ks] = __builtin_bit_cast(bf16x8, u);
      }
      floatx4 acc[4];
#pragma unroll
      for (int nt = 0; nt < 4; ++nt){
        acc[nt] = (floatx4){0.f, 0.f, 0.f, 0.f};
#pragma unroll
        for (int ks = 0; ks < 4; ++ks)
          acc[nt] = __builtin_amdgcn_mfma_f32_16x16x32_bf16(af[ks], bfr[nt][ks], acc[nt], 0, 0, 0);
      }
#pragma unroll
      for (int r = 0; r < 4; ++r){
        float s = 0.f;
#pragma unroll
        for (int nt = 0; nt < 4; ++nt)
          s = fmaf(fmaxf(acc[nt][r] + b2v[nt], 0.f), w3v[nt], s);
#pragma unroll
        for (int m = 8; m >= 1; m >>= 1) s += __shfl_xor(s, m);
        if (l16 == 0)
          p.pflow[c*1024 + i*32 + j0 + quad*4 + r] = softplusf_(s + b3);
      }
    }
  }
  __threadfence();
  grid.sync();

  // ---- P3: greedy (blocks 0..127; verified R8) ----
  if (bid < 128){
    float* pf_s = (float*)smem_raw;
    float* ef_s = pf_s + 1024;
    float* px = ef_s + 1024;
    float* py = px + 32;
    int* gl = (int*)(py + 32);
    int* order_s = gl + 32;
    int c = bid;
    for (int e = t; e < 1024; e += 256) pf_s[e] = p.pflow[c*1024 + e];
    if (t < 32){
      float2 p2 = ((const float2*)p.pos_c)[c*NK + t];
      px[t] = p2.x; py[t] = p2.y;
      gl[t] = p.g[c*NK + t];
    }
    __syncthreads();
    for (int e = t; e < 1024; e += 256){
      int ii = e >> 5, jj = e & 31;
      float dx = px[ii] - px[jj], dy = py[ii] - py[jj];
      float d = sqrtf(fmaf(dx, dx, dy*dy));
      float ds = d * (1.0f/1000.0f);
      float acc = p.en_b2[0];
#pragma unroll
      for (int q = 0; q < 16; ++q)
        acc = fmaf(fmaxf(fmaf(ds, p.en_w1[q], p.en_b1[q]), 0.f), p.en_w2[q], acc);
      ef_s[e] = 0.85f + 0.13f*sigmoidf_(acc);
    }
    if (t < 64){
      int tl = t & 31;
      float pr = (t < 32) ? p.prio_c[c*NK + t] : -1e30f;
      int rank = 0;
      for (int k = 0; k < 32; ++k){
        float pk = __shfl(pr, k, 32);
        rank += ((pk > pr) || (pk == pr && k < tl)) ? 1 : 0;
      }
      if (t < 32) order_s[rank] = t;
    }
    __syncthreads();
    if (t < 64){
      int tl = t & 31;
      int b = order_s[tl];
      float net0 = p.net_c[c*NK + b];
      float dnet = net0;
      float recv = 0.f;
      float ctotal = 0.f;
      for (int i = 0; i < 32; ++i){
        int a = order_s[i];
        float av0 = fmaxf(__shfl(net0, i, 32), 0.f);
        float pf = pf_s[a*32 + b];
        float ef = ef_s[a*32 + b];
        float needed = -dnet;
        float m = (needed > 0.f) ? fminf(needed, pf) : 0.f;
        float s = m;
#pragma unroll
        for (int dd = 1; dd < 32; dd <<= 1){
          float u = __shfl_up(s, dd, 32);
          if (tl >= dd) s += u;
        }
        float Se = __shfl_up(s, 1, 32);
        if (tl == 0) Se = 0.f;
        float rprev = fmaxf(av0 - Se, 0.f);
        int act = (rprev > 0.f) && (needed > 0.f);
        float f = fminf(m, rprev);
        dnet = fmaf(f, ef, dnet);
        recv = fmaf(f, ef, recv);
        if (t < 32){
          p.fl_c[c*1024 + a*32 + b] = f;
          p.ef_c[c*1024 + a*32 + b] = act ? ef : 1.0f;
        }
        float rs = f;
        for (int mm = 16; mm >= 1; mm >>= 1) rs += __shfl_xor(rs, mm, 32);
        if (t == 0){ p.esent[gl[a]] = rs; ctotal += rs; }
      }
      if (t < 32){
        p.nafter[gl[b]] = dnet;
        p.erecv[gl[b]]  = recv;
      }
      if (t == 0) atomicAdd(p.total, ctotal);
    }
  }
  __threadfence();
  grid.sync();

  // ---- P4: stream outputs (verified R8; 8 rows/block) ----
  {
    float* rowS = (float*)smem_raw;
    float* rowE = rowS + 4096;
    int* cols = (int*)(rowE + 4096);
    float* vals = (float*)(cols + 32);
    float* vale = vals + 32;
    float4 z4 = make_float4(0.f, 0.f, 0.f, 0.f);
    float4 o4 = make_float4(1.f, 1.f, 1.f, 1.f);
    float4* s4 = (float4*)rowS;
    float4* e4 = (float4*)rowE;
    for (int rr = 0; rr < 8; ++rr){
      int r = bid*8 + rr;
      int ra = p.row_of[r];
      int c2 = ra >> 5, a = ra & 31;
      if (t < 32){
        cols[t] = p.g[c2*NK + t];
        vals[t] = p.fl_c[c2*1024 + a*32 + t];
        vale[t] = p.ef_c[c2*1024 + a*32 + t];
      }
#pragma unroll
      for (int q = 0; q < 4; ++q){ s4[t + 256*q] = z4; e4[t + 256*q] = o4; }
      __syncthreads();
      if (t < 32){ rowS[cols[t]] = vals[t]; rowE[cols[t]] = vale[t]; }
      __syncthreads();
      float4* gs = (float4*)(p.sharing + (long)r*NB);
      float4* ge = (float4*)(p.effm    + (long)r*NB);
#pragma unroll
      for (int q = 0; q < 4; ++q){ gs[t + 256*q] = s4[t + 256*q]; ge[t + 256*q] = e4[t + 256*q]; }
      __syncthreads();
    }
  }
}

// ================== PATH B: proven R9 five-kernel fallback ==================
__global__ void k_prep_group(const float* __restrict__ fp_w1, const float* __restrict__ ps_w1,
                             const float* __restrict__ fp_b1, const float* __restrict__ fp_w2,
                             const int* __restrict__ assign, const int* __restrict__ hourp,
                             float* __restrict__ w1at, float* __restrict__ w1bt,
                             float* __restrict__ ps_w1t, int* __restrict__ g,
                             int* __restrict__ row_of, float* __restrict__ w1d_c,
                             float* __restrict__ bzc, uint4* __restrict__ w2f,
                             float* __restrict__ total){
  int bid = blockIdx.x;
  int t = threadIdx.x;
  if (bid < 80){
    int idx = bid*256 + t;
    if (idx < 128*128){
      int o = idx >> 7, e = idx & 127;
      w1at[e*128 + o] = fp_w1[o*258 + e];
      w1bt[e*128 + o] = fp_w1[o*258 + 128 + e];
    } else {
      int i2 = idx - 128*128;
      if (i2 < 128*32){
        int e = i2 >> 5, q = i2 & 31;
        ps_w1t[e*32 + q] = ps_w1[q*128 + e];
      }
    }
  } else if (bid < 96){
    __shared__ int hist[NC];
    __shared__ int loc[256];
    int start = (bid - 80)*256;
    for (int c = t; c < NC; c += 256) hist[c] = 0;
    __syncthreads();
    for (int j = t; j < start; j += 256) atomicAdd(&hist[assign[j]], 1);
    int i = start + t;
    int c = assign[i];
    loc[t] = c;
    __syncthreads();
    int r = hist[c];
    for (int j = 0; j < 256; ++j) r += (j < t && loc[j] == c) ? 1 : 0;
    if (r >= NK) r = NK - 1;
    g[c*NK + r] = i;
    row_of[i] = c*NK + r;
  } else if (bid == 96){
    if (t < 128){
      float hour_f = (float)hourp[0] / 24.0f;
      w1d_c[t] = fp_w1[t*258 + 256];
      bzc[t]   = fmaf(hour_f, fp_w1[t*258 + 257], fp_b1[t]);
    }
    if (t == 128) total[0] = 0.f;
  } else {
    for (int ff = t; ff < 1024; ff += 256){
      int lane = ff & 63, fi = ff >> 6;
      int nt = fi >> 2, ks = fi & 3;
      int o = nt*16 + (lane & 15);
      int kb = ks*32 + (lane >> 4)*8;
      const float* src = fp_w2 + o*128 + kb;
      uint4 u;
      u.x = pack_bf16(src[0], src[1]);
      u.y = pack_bf16(src[2], src[3]);
      u.z = pack_bf16(src[4], src[5]);
      u.w = pack_bf16(src[6], src[7]);
      w2f[ff] = u;
    }
  }
}

__global__ void k_hijprio(const float* __restrict__ emb, const float* __restrict__ gen,
                          const float* __restrict__ cons, const float* __restrict__ pos,
                          const float* __restrict__ w1at, const float* __restrict__ w1bt,
                          const float* __restrict__ ps_w1t, const float* __restrict__ ps_b1,
                          const float* __restrict__ ps_w2, const float* __restrict__ ps_b2,
                          const int* __restrict__ row_of, const int* __restrict__ hourp,
                          float* __restrict__ hi_c, float* __restrict__ hj_c,
                          float* __restrict__ net_c, float* __restrict__ prio_c,
                          float* __restrict__ pos_c){
  __shared__ float es[8*132];
  __shared__ float wsm[128*32];
  int t = threadIdx.x;
  int i0 = blockIdx.x*8;
  for (int idx = t; idx < 8*128; idx += 256){
    int b = idx >> 7, e = idx & 127;
    es[b*132 + e] = emb[(i0 + b)*128 + e];
  }
  for (int idx = t; idx < 128*32; idx += 256) wsm[idx] = ps_w1t[idx];
  __syncthreads();
  {
    int o = t & 127, half = t >> 7;
    float ai[4], aj[4];
#pragma unroll
    for (int r = 0; r < 4; ++r){ ai[r] = 0.f; aj[r] = 0.f; }
    for (int e = 0; e < 128; e += 4){
      float wa0 = w1at[(e+0)*128 + o], wa1 = w1at[(e+1)*128 + o];
      float wa2 = w1at[(e+2)*128 + o], wa3 = w1at[(e+3)*128 + o];
      float wb0 = w1bt[(e+0)*128 + o], wb1 = w1bt[(e+1)*128 + o];
      float wb2 = w1bt[(e+2)*128 + o], wb3 = w1bt[(e+3)*128 + o];
#pragma unroll
      for (int r = 0; r < 4; ++r){
        float4 ev = *(const float4*)&es[(half*4 + r)*132 + e];
        ai[r] = fmaf(ev.x, wa0, fmaf(ev.y, wa1, fmaf(ev.z, wa2, fmaf(ev.w, wa3, ai[r]))));
        aj[r] = fmaf(ev.x, wb0, fmaf(ev.y, wb1, fmaf(ev.z, wb2, fmaf(ev.w, wb3, aj[r]))));
      }
    }
#pragma unroll
    for (int r = 0; r < 4; ++r){
      int b = i0 + half*4 + r;
      int ck = row_of[b];
      hi_c[ck*128 + o] = ai[r];
      hj_c[ck*128 + o] = aj[r];
    }
  }
  {
    int bl = t >> 5, q = t & 31;
    int i = i0 + bl;
    float acc = ps_b1[q];
    const float* er = &es[bl*132];
    for (int e = 0; e < 128; ++e) acc = fmaf(er[e], wsm[e*32 + q], acc);
    float v = fmaxf(acc, 0.f) * ps_w2[q];
    for (int m = 16; m >= 1; m >>= 1) v += __shfl_xor(v, m, 32);
    if (q == 0){
      int ck = row_of[i];
      prio_c[ck] = sigmoidf_(v + ps_b2[0]);
      int h = hourp[0];
      net_c[ck] = gen[i*24 + h] - cons[i*24 + h];
      pos_c[2*ck]   = pos[2*i];
      pos_c[2*ck+1] = pos[2*i+1];
    }
  }
}

__global__ __launch_bounds__(256) void k_pflow(
    const float* __restrict__ hi_c, const float* __restrict__ hj_c,
    const float* __restrict__ pos_c, const float* __restrict__ w1d_c,
    const float* __restrict__ bzc, const uint4* __restrict__ w2f,
    const float* __restrict__ fp_b2, const float* __restrict__ fp_w3,
    const float* __restrict__ fp_b3, float* __restrict__ pflow){
  int t = threadIdx.x;
  int lane = t & 63, wv = t >> 6;
  int gw = blockIdx.x*4 + wv;
  int c = gw >> 6;
  int rem = gw & 63;
  int i = rem >> 1, j0 = (rem & 1)*16;
  int l16 = lane & 15, quad = lane >> 4;
  int j = j0 + l16;
  float xi = pos_c[(c*NK + i)*2 + 0], yi = pos_c[(c*NK + i)*2 + 1];
  float xj = pos_c[(c*NK + j)*2 + 0], yj = pos_c[(c*NK + j)*2 + 1];
  float dx = xi - xj, dy = yi - yj;
  float d = sqrtf(fmaf(dx, dx, dy*dy));
  const float4* hi4 = (const float4*)(hi_c + (c*NK + i)*128);
  const float4* hj4 = (const float4*)(hj_c + (c*NK + j)*128);
  const float4* wd4 = (const float4*)w1d_c;
  const float4* bz4 = (const float4*)bzc;
  bf16x8 af[4];
#pragma unroll
  for (int ks = 0; ks < 4; ++ks){
    int q8 = ks*8 + quad*2;
    float4 a0 = hi4[q8], a1 = hi4[q8 + 1];
    float4 b0 = hj4[q8], b1 = hj4[q8 + 1];
    float4 w0 = wd4[q8], w1 = wd4[q8 + 1];
    float4 z0 = bz4[q8], z1 = bz4[q8 + 1];
    float v0 = fmaxf(a0.x + b0.x + fmaf(d, w0.x, z0.x), 0.f);
    float v1 = fmaxf(a0.y + b0.y + fmaf(d, w0.y, z0.y), 0.f);
    float v2 = fmaxf(a0.z + b0.z + fmaf(d, w0.z, z0.z), 0.f);
    float v3 = fmaxf(a0.w + b0.w + fmaf(d, w0.w, z0.w), 0.f);
    float v4 = fmaxf(a1.x + b1.x + fmaf(d, w1.x, z1.x), 0.f);
    float v5 = fmaxf(a1.y + b1.y + fmaf(d, w1.y, z1.y), 0.f);
    float v6 = fmaxf(a1.z + b1.z + fmaf(d, w1.z, z1.z), 0.f);
    float v7 = fmaxf(a1.w + b1.w + fmaf(d, w1.w, z1.w), 0.f);
    uint4 u;
    u.x = pack_bf16(v0, v1);
    u.y = pack_bf16(v2, v3);
    u.z = pack_bf16(v4, v5);
    u.w = pack_bf16(v6, v7);
    af[ks] = __builtin_bit_cast(bf16x8, u);
  }
  bf16x8 bfr[4][4];
#pragma unroll
  for (int nt = 0; nt < 4; ++nt)
#pragma unroll
    for (int ks = 0; ks < 4; ++ks)
      bfr[nt][ks] = __builtin_bit_cast(bf16x8, w2f[(nt*4 + ks)*64 + lane]);
  floatx4 acc[4];
#pragma unroll
  for (int nt = 0; nt < 4; ++nt){
    acc[nt] = (floatx4){0.f, 0.f, 0.f, 0.f};
#pragma unroll
    for (int ks = 0; ks < 4; ++ks)
      acc[nt] = __builtin_amdgcn_mfma_f32_16x16x32_bf16(af[ks], bfr[nt][ks], acc[nt], 0, 0, 0);
  }
  float b2v[4], w3v[4];
#pragma unroll
  for (int nt = 0; nt < 4; ++nt){
    b2v[nt] = fp_b2[nt*16 + l16];
    w3v[nt] = fp_w3[nt*16 + l16];
  }
  float b3 = fp_b3[0];
#pragma unroll
  for (int r = 0; r < 4; ++r){
    float s = 0.f;
#pragma unroll
    for (int nt = 0; nt < 4; ++nt)
      s = fmaf(fmaxf(acc[nt][r] + b2v[nt], 0.f), w3v[nt], s);
#pragma unroll
    for (int m = 8; m >= 1; m >>= 1) s += __shfl_xor(s, m);
    if (l16 == 0)
      pflow[c*1024 + i*32 + j0 + quad*4 + r] = softplusf_(s + b3);
  }
}

__global__ __launch_bounds__(64) void k_greedy(
    const float* __restrict__ net_c, const float* __restrict__ prio_c,
    const float* __restrict__ pos_c, const float* __restrict__ en_w1,
    const float* __restrict__ en_b1, const float* __restrict__ en_w2,
    const float* __restrict__ en_b2, const float* __restrict__ pflow,
    const int* __restrict__ g,
    float* __restrict__ fl_c, float* __restrict__ ef_c, float* __restrict__ total,
    float* __restrict__ esent, float* __restrict__ erecv, float* __restrict__ nafter){
  __shared__ float pf_s[1024];
  __shared__ float ef_s[1024];
  __shared__ float fl_s[1024];
  __shared__ float efm_s[1024];
  __shared__ float px[32], py[32];
  __shared__ int order_s[32];
  __shared__ int gl[32];
  int t = threadIdx.x;
  int tl = t & 31;
  int c = blockIdx.x;
  for (int e = t; e < 1024; e += 64) pf_s[e] = pflow[c*1024 + e];
  if (t < 32){
    float2 p2 = ((const float2*)pos_c)[c*NK + t];
    px[t] = p2.x; py[t] = p2.y;
    gl[t] = g[c*NK + t];
  }
  __syncthreads();
  for (int e = t; e < 1024; e += 64){
    int ii = e >> 5, jj = e & 31;
    float dx = px[ii] - px[jj], dy = py[ii] - py[jj];
    float d = sqrtf(fmaf(dx, dx, dy*dy));
    float ds = d * (1.0f/1000.0f);
    float acc = en_b2[0];
#pragma unroll
    for (int q = 0; q < 16; ++q)
      acc = fmaf(fmaxf(fmaf(ds, en_w1[q], en_b1[q]), 0.f), en_w2[q], acc);
    ef_s[e] = 0.85f + 0.13f*sigmoidf_(acc);
  }
  float p = (t < 32) ? prio_c[c*NK + t] : -1e30f;
  int rank = 0;
  for (int k = 0; k < 32; ++k){
    float pk = __shfl(p, k, 32);
    rank += ((pk > p) || (pk == p && k < tl)) ? 1 : 0;
  }
  if (t < 32) order_s[rank] = t;
  __syncthreads();
  int b = order_s[tl];
  float net0 = net_c[c*NK + b];
  float dnet = net0;
  float recv = 0.f;
  float ctotal = 0.f;
  for (int i = 0; i < 32; ++i){
    int a = order_s[i];
    float av0 = fmaxf(__shfl(net0, i, 32), 0.f);
    float pf = pf_s[a*32 + b];
    float ef = ef_s[a*32 + b];
    float needed = -dnet;
    float m = (needed > 0.f) ? fminf(needed, pf) : 0.f;
    float s = m;
#pragma unroll
    for (int dd = 1; dd < 32; dd <<= 1){
      float u = __shfl_up(s, dd, 32);
      if (tl >= dd) s += u;
    }
    float Se = __shfl_up(s, 1, 32);
    if (tl == 0) Se = 0.f;
    float rprev = fmaxf(av0 - Se, 0.f);
    int act = (rprev > 0.f) && (needed > 0.f);
    float f = fminf(m, rprev);
    dnet = fmaf(f, ef, dnet);
    recv = fmaf(f, ef, recv);
    if (t < 32){
      fl_s[a*32 + b]  = f;
      efm_s[a*32 + b] = act ? ef : 1.0f;
    }
    float rs = f;
    for (int mm = 16; mm >= 1; mm >>= 1) rs += __shfl_xor(rs, mm, 32);
    if (t == 0){ esent[gl[a]] = rs; ctotal += rs; }
  }
  if (t < 32){
    nafter[gl[b]] = dnet;
    erecv[gl[b]]  = recv;
  }
  if (t == 0) atomicAdd(total, ctotal);
  __syncthreads();
  for (int e = t; e < 1024; e += 64){
    fl_c[c*1024 + e] = fl_s[e];
    ef_c[c*1024 + e] = efm_s[e];
  }
}

__global__ __launch_bounds__(256) void k_write(
    const float* __restrict__ fl_c, const float* __restrict__ ef_c,
    const int* __restrict__ g, const int* __restrict__ row_of,
    float* __restrict__ sharing, float* __restrict__ effm){
  __shared__ float rowS[4096];
  __shared__ float rowE[4096];
  __shared__ int   cols[32];
  __shared__ float vals[32];
  __shared__ float vale[32];
  int t = threadIdx.x;
  int r = blockIdx.x;
  int ra = row_of[r];
  int c = ra >> 5, a = ra & 31;
  if (t < 32){
    cols[t] = g[c*NK + t];
    vals[t] = fl_c[c*1024 + a*32 + t];
    vale[t] = ef_c[c*1024 + a*32 + t];
  }
  float4 z4 = make_float4(0.f, 0.f, 0.f, 0.f);
  float4 o4 = make_float4(1.f, 1.f, 1.f, 1.f);
  float4* s4 = (float4*)rowS;
  float4* e4 = (float4*)rowE;
#pragma unroll
  for (int q = 0; q < 4; ++q){ s4[t + 256*q] = z4; e4[t + 256*q] = o4; }
  __syncthreads();
  if (t < 32){ rowS[cols[t]] = vals[t]; rowE[cols[t]] = vale[t]; }
  __syncthreads();
  float4* gs = (float4*)(sharing + (long)r*NB);
  float4* ge = (float4*)(effm    + (long)r*NB);
#pragma unroll
  for (int q = 0; q < 4; ++q){ gs[t + 256*q] = s4[t + 256*q]; ge[t + 256*q] = e4[t + 256*q]; }
}

extern "C" void kernel_launch(void* const* d_in, const int* in_sizes, int n_in,
                              void* d_out, int out_size, void* d_ws, size_t ws_size,
                              hipStream_t stream){
  (void)in_sizes; (void)n_in; (void)out_size; (void)ws_size;
  KParams prm;
  prm.emb   = (const float*)d_in[0];
  prm.gen   = (const float*)d_in[1];
  prm.cons  = (const float*)d_in[2];
  prm.pos   = (const float*)d_in[3];
  prm.fp_w1 = (const float*)d_in[4];
  prm.fp_b1 = (const float*)d_in[5];
  prm.fp_w2 = (const float*)d_in[6];
  prm.fp_b2 = (const float*)d_in[7];
  prm.fp_w3 = (const float*)d_in[8];
  prm.fp_b3 = (const float*)d_in[9];
  prm.en_w1 = (const float*)d_in[10];
  prm.en_b1 = (const float*)d_in[11];
  prm.en_w2 = (const float*)d_in[12];
  prm.en_b2 = (const float*)d_in[13];
  prm.ps_w1 = (const float*)d_in[14];
  prm.ps_b1 = (const float*)d_in[15];
  prm.ps_w2 = (const float*)d_in[16];
  prm.ps_b2 = (const float*)d_in[17];
  prm.assign = (const int*)d_in[18];
  prm.hourp  = (const int*)d_in[20];

  // Shared workspace map (audited; used by BOTH paths):
  char* ws = (char*)d_ws;
  prm.w1at   = (float*)(ws + 0);          // [0,       65536)
  prm.w1bt   = (float*)(ws + 65536);      // [65536,   131072)
  prm.ps_w1t = (float*)(ws + 131072);     // [131072,  147456)
  prm.g      = (int*)  (ws + 147456);     // [147456,  163840)
  prm.row_of = (int*)  (ws + 163840);     // [163840,  180224)
  prm.net_c  = (float*)(ws + 180224);     // [180224,  196608)
  prm.prio_c = (float*)(ws + 196608);     // [196608,  212992)
  prm.pos_c  = (float*)(ws + 212992);     // [212992,  245760)
  prm.w1d_c  = (float*)(ws + 245760);     // [245760,  246272)
  prm.bzc    = (float*)(ws + 246272);     // [246272,  246784)
  prm.w2f    = (uint4*)(ws + 262144);     // [262144,  278528)
  prm.hi_c   = (float*)(ws + 524288);     // [524288,  2621440)
  prm.hj_c   = (float*)(ws + 2621440);    // [2621440, 4718592)
  prm.pflow  = (float*)(ws + 4718592);    // [4718592, 5242880)
  prm.fl_c   = (float*)(ws + 5242880);    // [5242880, 5767168)
  prm.ef_c   = (float*)(ws + 5767168);    // [5767168, 6291456)

  prm.sharing = (float*)d_out;
  prm.effm    = prm.sharing + (long)NB*NB;
  prm.total   = prm.effm + (long)NB*NB;
  prm.esent   = prm.total + 1;
  prm.erecv   = prm.esent + NB;
  prm.nafter  = prm.erecv + NB;

  // Deterministic host-side occupancy check (capture-safe, no alloc/sync):
  // cooperative 512-block launch requires >= 2 co-resident blocks/CU.
  int maxb = 0;
  hipError_t oe = hipOccupancyMaxActiveBlocksPerMultiprocessor(
      &maxb, reinterpret_cast<const void*>(&k_fused), 256, 0);
  bool coop_ok = (oe == hipSuccess) && (maxb >= 2);

  if (coop_ok){
    void* args[] = { &prm };
    hipLaunchCooperativeKernel((void*)k_fused, dim3(512), dim3(256), args, 0, stream);
  } else {
    hipLaunchKernelGGL(k_prep_group, dim3(98), dim3(256), 0, stream,
                       prm.fp_w1, prm.ps_w1, prm.fp_b1, prm.fp_w2, prm.assign, prm.hourp,
                       prm.w1at, prm.w1bt, prm.ps_w1t, prm.g, prm.row_of, prm.w1d_c,
                       prm.bzc, prm.w2f, prm.total);
    hipLaunchKernelGGL(k_hijprio, dim3(512), dim3(256), 0, stream,
                       prm.emb, prm.gen, prm.cons, prm.pos, prm.w1at, prm.w1bt,
                       prm.ps_w1t, prm.ps_b1, prm.ps_w2, prm.ps_b2,
                       prm.row_of, prm.hourp, prm.hi_c, prm.hj_c, prm.net_c,
                       prm.prio_c, prm.pos_c);
    hipLaunchKernelGGL(k_pflow, dim3(2048), dim3(256), 0, stream,
                       prm.hi_c, prm.hj_c, prm.pos_c, prm.w1d_c, prm.bzc, prm.w2f,
                       prm.fp_b2, prm.fp_w3, prm.fp_b3, prm.pflow);
    hipLaunchKernelGGL(k_greedy, dim3(128), dim3(64), 0, stream,
                       prm.net_c, prm.prio_c, prm.pos_c, prm.en_w1, prm.en_b1,
                       prm.en_w2, prm.en_b2, prm.pflow, prm.g,
                       prm.fl_c, prm.ef_c, prm.total, prm.esent, prm.erecv, prm.nafter);
    hipLaunchKernelGGL(k_write, dim3(4096), dim3(256), 0, stream,
                       prm.fl_c, prm.ef_c, prm.g, prm.row_of, prm.sharing, prm.effm);
  }
}

// Round 12
// 263.461 us; speedup vs baseline: 1.0064x; 1.0064x over previous
//
#include <hip/hip_runtime.h>
#include <math.h>

#define NB 4096
#define NC 128
#define NK 32
#define NE 128

typedef __bf16 bf16x8 __attribute__((ext_vector_type(8)));
typedef float floatx4 __attribute__((ext_vector_type(4)));

__device__ __forceinline__ float sigmoidf_(float x){
  if (x >= 0.f){ float z = expf(-x); return 1.f/(1.f+z); }
  float z = expf(x); return z/(1.f+z);
}
__device__ __forceinline__ float softplusf_(float x){
  return fmaxf(x, 0.f) + log1pf(expf(-fabsf(x)));
}
__device__ __forceinline__ unsigned int pack_bf16(float a, float b){
  unsigned short ua = __builtin_bit_cast(unsigned short, (__bf16)a);
  unsigned short ub = __builtin_bit_cast(unsigned short, (__bf16)b);
  return (unsigned int)ua | ((unsigned int)ub << 16);
}

// ================= K1: hij GEMM + prio MLP (natural order) + grouping + consts + w2f =========
// blocks 0..511: hij+prio for 8 buildings each. W1 rows read DIRECTLY from fp_w1 (L2-resident,
// all blocks share 128KB) — removes the prep->hij dependency. Outputs in natural building
// order (no row_of needed here). blocks 512..527: counting-sort grouping; 528: consts+total;
// 529: W2 MFMA-fragment pack. No intra-grid dependencies.
__global__ void k_hijprio(const float* __restrict__ emb, const float* __restrict__ gen,
                          const float* __restrict__ cons, const float* __restrict__ fp_w1,
                          const float* __restrict__ fp_b1, const float* __restrict__ fp_w2,
                          const float* __restrict__ ps_w1, const float* __restrict__ ps_b1,
                          const float* __restrict__ ps_w2, const float* __restrict__ ps_b2,
                          const int* __restrict__ assign, const int* __restrict__ hourp,
                          float* __restrict__ hi, float* __restrict__ hj,
                          float* __restrict__ net, float* __restrict__ prio,
                          int* __restrict__ g, int* __restrict__ row_of,
                          float* __restrict__ w1d_c, float* __restrict__ bzc,
                          uint4* __restrict__ w2f, float* __restrict__ total){
  int bid = blockIdx.x;
  int t = threadIdx.x;
  if (bid < 512){
    __shared__ float es[8*132];
    __shared__ float wsm[128*33];     // ps_w1 transposed: wsm[e*33+q]; +1 pad kills both-way conflicts
    int i0 = bid*8;
    for (int idx = t; idx < 8*128; idx += 256){
      int b = idx >> 7, e = idx & 127;
      es[b*132 + e] = emb[(i0 + b)*128 + e];
    }
    for (int idx = t; idx < 4096; idx += 256){
      int q = idx >> 7, e = idx & 127;          // read ps_w1[q*128+e] coalesced
      wsm[e*33 + q] = ps_w1[q*128 + e];         // padded scatter: lanes hit distinct banks
    }
    __syncthreads();
    // ---- hij (f32, precision-critical; identical fmaf nesting, W1 values identical) ----
    {
      int o = t & 127, half = t >> 7;
      const float* w1r = fp_w1 + o*258;         // this thread's W1 row (L2-hot)
      float ai[4], aj[4];
#pragma unroll
      for (int r = 0; r < 4; ++r){ ai[r] = 0.f; aj[r] = 0.f; }
      for (int e = 0; e < 128; e += 4){
        float wa0 = w1r[e+0], wa1 = w1r[e+1], wa2 = w1r[e+2], wa3 = w1r[e+3];
        float wb0 = w1r[128+e+0], wb1 = w1r[128+e+1], wb2 = w1r[128+e+2], wb3 = w1r[128+e+3];
#pragma unroll
        for (int r = 0; r < 4; ++r){
          float4 ev = *(const float4*)&es[(half*4 + r)*132 + e];
          ai[r] = fmaf(ev.x, wa0, fmaf(ev.y, wa1, fmaf(ev.z, wa2, fmaf(ev.w, wa3, ai[r]))));
          aj[r] = fmaf(ev.x, wb0, fmaf(ev.y, wb1, fmaf(ev.z, wb2, fmaf(ev.w, wb3, aj[r]))));
        }
      }
#pragma unroll
      for (int r = 0; r < 4; ++r){
        int b = i0 + half*4 + r;
        hi[b*128 + o] = ai[r];                  // natural order — consumers gather via g
        hj[b*128 + o] = aj[r];
      }
    }
    // ---- prio (f32 exact; same chain/shfl tree; natural order) ----
    {
      int bl = t >> 5, q = t & 31;
      int i = i0 + bl;
      float acc = ps_b1[q];
      const float* er = &es[bl*132];
      for (int e = 0; e < 128; ++e) acc = fmaf(er[e], wsm[e*33 + q], acc);
      float v = fmaxf(acc, 0.f) * ps_w2[q];
      for (int m = 16; m >= 1; m >>= 1) v += __shfl_xor(v, m, 32);
      if (q == 0){
        prio[i] = sigmoidf_(v + ps_b2[0]);
        int h = hourp[0];
        net[i] = gen[i*24 + h] - cons[i*24 + h];
      }
    }
  } else if (bid < 528){
    __shared__ int hist[NC];
    __shared__ int loc[256];
    int start = (bid - 512)*256;
    for (int c = t; c < NC; c += 256) hist[c] = 0;
    __syncthreads();
    for (int j = t; j < start; j += 256) atomicAdd(&hist[assign[j]], 1);
    int i = start + t;
    int c = assign[i];
    loc[t] = c;
    __syncthreads();
    int r = hist[c];
    for (int j = 0; j < 256; ++j) r += (j < t && loc[j] == c) ? 1 : 0;
    if (r >= NK) r = NK - 1;
    g[c*NK + r] = i;
    row_of[i] = c*NK + r;
  } else if (bid == 528){
    if (t < 128){
      float hour_f = (float)hourp[0] / 24.0f;
      w1d_c[t] = fp_w1[t*258 + 256];
      bzc[t]   = fmaf(hour_f, fp_w1[t*258 + 257], fp_b1[t]);
    }
    if (t == 128) total[0] = 0.f;
  } else {
    // W2 fragments: frag f=(nt*4+ks)*64+lane holds W2[o=nt*16+(lane&15)][ks*32+(lane>>4)*8 + 0..7]
    for (int ff = t; ff < 1024; ff += 256){
      int lane = ff & 63, fi = ff >> 6;
      int nt = fi >> 2, ks = fi & 3;
      int o = nt*16 + (lane & 15);
      int kb = ks*32 + (lane >> 4)*8;
      const float* src = fp_w2 + o*128 + kb;
      uint4 u;
      u.x = pack_bf16(src[0], src[1]);
      u.y = pack_bf16(src[2], src[3]);
      u.z = pack_bf16(src[4], src[5]);
      u.w = pack_bf16(src[6], src[7]);
      w2f[ff] = u;
    }
  }
}

// ================= K2: pflow (MFMA -> LDS) + eff + greedy, one block per cluster ==============
// 128 blocks x 256 thr. Per-tile MFMA math identical to R9 k_pflow (tiles independent ->
// wave remapping changes nothing); pf never round-trips through global. Greedy body = R9.
__global__ __launch_bounds__(256) void k_pfgreedy(
    const float* __restrict__ hi, const float* __restrict__ hj,
    const float* __restrict__ pos, const float* __restrict__ net,
    const float* __restrict__ prio, const float* __restrict__ w1d_c,
    const float* __restrict__ bzc, const uint4* __restrict__ w2f,
    const float* __restrict__ fp_b2, const float* __restrict__ fp_w3,
    const float* __restrict__ fp_b3, const float* __restrict__ en_w1,
    const float* __restrict__ en_b1, const float* __restrict__ en_w2,
    const float* __restrict__ en_b2, const int* __restrict__ g,
    float* __restrict__ fl_c, float* __restrict__ ef_c, float* __restrict__ total,
    float* __restrict__ esent, float* __restrict__ erecv, float* __restrict__ nafter){
  __shared__ float pf_s[1024];
  __shared__ float ef_s[1024];
  __shared__ float px[32], py[32];
  __shared__ int gl[32];
  __shared__ int order_s[32];
  int t = threadIdx.x;
  int lane = t & 63, wv = t >> 6;
  int c = blockIdx.x;
  if (t < 32){
    int b = g[c*NK + t];
    gl[t] = b;
    px[t] = pos[2*b];
    py[t] = pos[2*b + 1];
  }
  __syncthreads();
  // ---- pflow: 64 (i,j0) tiles, 4 waves x 16 iterations; per-tile math = R9 k_pflow ----
  {
    int l16 = lane & 15, quad = lane >> 4;
    bf16x8 bfr[4][4];
#pragma unroll
    for (int nt = 0; nt < 4; ++nt)
#pragma unroll
      for (int ks = 0; ks < 4; ++ks)
        bfr[nt][ks] = __builtin_bit_cast(bf16x8, w2f[(nt*4 + ks)*64 + lane]);
    float b2v[4], w3v[4];
#pragma unroll
    for (int nt = 0; nt < 4; ++nt){
      b2v[nt] = fp_b2[nt*16 + l16];
      w3v[nt] = fp_w3[nt*16 + l16];
    }
    float b3 = fp_b3[0];
    const float4* wd4 = (const float4*)w1d_c;
    const float4* bz4 = (const float4*)bzc;
    for (int it = 0; it < 16; ++it){
      int tile = it*4 + wv;                 // 0..63
      int i = tile >> 1, j0 = (tile & 1)*16;
      int j = j0 + l16;
      float dx = px[i] - px[j], dy = py[i] - py[j];
      float d = sqrtf(fmaf(dx, dx, dy*dy));
      const float4* hi4 = (const float4*)(hi + gl[i]*128);
      const float4* hj4 = (const float4*)(hj + gl[j]*128);
      bf16x8 af[4];
#pragma unroll
      for (int ks = 0; ks < 4; ++ks){
        int q8 = ks*8 + quad*2;
        float4 a0 = hi4[q8], a1 = hi4[q8 + 1];
        float4 b0 = hj4[q8], b1 = hj4[q8 + 1];
        float4 w0 = wd4[q8], w1 = wd4[q8 + 1];
        float4 z0 = bz4[q8], z1 = bz4[q8 + 1];
        float v0 = fmaxf(a0.x + b0.x + fmaf(d, w0.x, z0.x), 0.f);
        float v1 = fmaxf(a0.y + b0.y + fmaf(d, w0.y, z0.y), 0.f);
        float v2 = fmaxf(a0.z + b0.z + fmaf(d, w0.z, z0.z), 0.f);
        float v3 = fmaxf(a0.w + b0.w + fmaf(d, w0.w, z0.w), 0.f);
        float v4 = fmaxf(a1.x + b1.x + fmaf(d, w1.x, z1.x), 0.f);
        float v5 = fmaxf(a1.y + b1.y + fmaf(d, w1.y, z1.y), 0.f);
        float v6 = fmaxf(a1.z + b1.z + fmaf(d, w1.z, z1.z), 0.f);
        float v7 = fmaxf(a1.w + b1.w + fmaf(d, w1.w, z1.w), 0.f);
        uint4 u;
        u.x = pack_bf16(v0, v1);
        u.y = pack_bf16(v2, v3);
        u.z = pack_bf16(v4, v5);
        u.w = pack_bf16(v6, v7);
        af[ks] = __builtin_bit_cast(bf16x8, u);
      }
      floatx4 acc[4];
#pragma unroll
      for (int nt = 0; nt < 4; ++nt){
        acc[nt] = (floatx4){0.f, 0.f, 0.f, 0.f};
#pragma unroll
        for (int ks = 0; ks < 4; ++ks)
          acc[nt] = __builtin_amdgcn_mfma_f32_16x16x32_bf16(af[ks], bfr[nt][ks], acc[nt], 0, 0, 0);
      }
#pragma unroll
      for (int r = 0; r < 4; ++r){
        float s = 0.f;
#pragma unroll
        for (int nt = 0; nt < 4; ++nt)
          s = fmaf(fmaxf(acc[nt][r] + b2v[nt], 0.f), w3v[nt], s);
#pragma unroll
        for (int m = 8; m >= 1; m >>= 1) s += __shfl_xor(s, m);
        if (l16 == 0)
          pf_s[i*32 + j0 + quad*4 + r] = softplusf_(s + b3);
      }
    }
  }
  // ---- eff tile (same arithmetic as R9 k_greedy) ----
  for (int e = t; e < 1024; e += 256){
    int ii = e >> 5, jj = e & 31;
    float dx = px[ii] - px[jj], dy = py[ii] - py[jj];
    float d = sqrtf(fmaf(dx, dx, dy*dy));
    float ds = d * (1.0f/1000.0f);
    float acc = en_b2[0];
#pragma unroll
    for (int q = 0; q < 16; ++q)
      acc = fmaf(fmaxf(fmaf(ds, en_w1[q], en_b1[q]), 0.f), en_w2[q], acc);
    ef_s[e] = 0.85f + 0.13f*sigmoidf_(acc);
  }
  if (t < 64){
    int tl = t & 31;
    float pr = (t < 32) ? prio[gl[t]] : -1e30f;
    int rank = 0;
    for (int k = 0; k < 32; ++k){
      float pk = __shfl(pr, k, 32);
      rank += ((pk > pr) || (pk == pr && k < tl)) ? 1 : 0;
    }
    if (t < 32) order_s[rank] = t;
  }
  __syncthreads();
  // ---- greedy allocation (R9 body; values identical) ----
  if (t < 64){
    int tl = t & 31;
    int b = order_s[tl];
    float net0 = net[gl[b]];
    float dnet = net0;
    float recv = 0.f;
    float ctotal = 0.f;
    for (int i = 0; i < 32; ++i){
      int a = order_s[i];
      float av0 = fmaxf(__shfl(net0, i, 32), 0.f);
      float pf = pf_s[a*32 + b];
      float ef = ef_s[a*32 + b];
      float needed = -dnet;
      float m = (needed > 0.f) ? fminf(needed, pf) : 0.f;
      float s = m;
#pragma unroll
      for (int dd = 1; dd < 32; dd <<= 1){
        float u = __shfl_up(s, dd, 32);
        if (tl >= dd) s += u;
      }
      float Se = __shfl_up(s, 1, 32);
      if (tl == 0) Se = 0.f;
      float rprev = fmaxf(av0 - Se, 0.f);
      int act = (rprev > 0.f) && (needed > 0.f);
      float f = fminf(m, rprev);
      dnet = fmaf(f, ef, dnet);
      recv = fmaf(f, ef, recv);
      if (t < 32){
        fl_c[c*1024 + a*32 + b] = f;
        ef_c[c*1024 + a*32 + b] = act ? ef : 1.0f;
      }
      float rs = f;
      for (int mm = 16; mm >= 1; mm >>= 1) rs += __shfl_xor(rs, mm, 32);
      if (t == 0){ esent[gl[a]] = rs; ctotal += rs; }
    }
    if (t < 32){
      nafter[gl[b]] = dnet;
      erecv[gl[b]]  = recv;
    }
    if (t == 0) atomicAdd(total, ctotal);
  }
}

// ================= K3: stream N x N outputs (R9 k_write verbatim) =============================
__global__ __launch_bounds__(256) void k_write(
    const float* __restrict__ fl_c, const float* __restrict__ ef_c,
    const int* __restrict__ g, const int* __restrict__ row_of,
    float* __restrict__ sharing, float* __restrict__ effm){
  __shared__ float rowS[4096];
  __shared__ float rowE[4096];
  __shared__ int   cols[32];
  __shared__ float vals[32];
  __shared__ float vale[32];
  int t = threadIdx.x;
  int r = blockIdx.x;
  int ra = row_of[r];
  int c = ra >> 5, a = ra & 31;
  if (t < 32){
    cols[t] = g[c*NK + t];
    vals[t] = fl_c[c*1024 + a*32 + t];
    vale[t] = ef_c[c*1024 + a*32 + t];
  }
  float4 z4 = make_float4(0.f, 0.f, 0.f, 0.f);
  float4 o4 = make_float4(1.f, 1.f, 1.f, 1.f);
  float4* s4 = (float4*)rowS;
  float4* e4 = (float4*)rowE;
#pragma unroll
  for (int q = 0; q < 4; ++q){ s4[t + 256*q] = z4; e4[t + 256*q] = o4; }
  __syncthreads();
  if (t < 32){ rowS[cols[t]] = vals[t]; rowE[cols[t]] = vale[t]; }
  __syncthreads();
  float4* gs = (float4*)(sharing + (long)r*NB);
  float4* ge = (float4*)(effm    + (long)r*NB);
#pragma unroll
  for (int q = 0; q < 4; ++q){ gs[t + 256*q] = s4[t + 256*q]; ge[t + 256*q] = e4[t + 256*q]; }
}

extern "C" void kernel_launch(void* const* d_in, const int* in_sizes, int n_in,
                              void* d_out, int out_size, void* d_ws, size_t ws_size,
                              hipStream_t stream){
  (void)in_sizes; (void)n_in; (void)out_size; (void)ws_size;
  const float* emb   = (const float*)d_in[0];
  const float* gen   = (const float*)d_in[1];
  const float* cons  = (const float*)d_in[2];
  const float* pos   = (const float*)d_in[3];
  const float* fp_w1 = (const float*)d_in[4];
  const float* fp_b1 = (const float*)d_in[5];
  const float* fp_w2 = (const float*)d_in[6];
  const float* fp_b2 = (const float*)d_in[7];
  const float* fp_w3 = (const float*)d_in[8];
  const float* fp_b3 = (const float*)d_in[9];
  const float* en_w1 = (const float*)d_in[10];
  const float* en_b1 = (const float*)d_in[11];
  const float* en_w2 = (const float*)d_in[12];
  const float* en_b2 = (const float*)d_in[13];
  const float* ps_w1 = (const float*)d_in[14];
  const float* ps_b1 = (const float*)d_in[15];
  const float* ps_w2 = (const float*)d_in[16];
  const float* ps_b2 = (const float*)d_in[17];
  const int*   assign = (const int*)d_in[18];
  const int*   hourp  = (const int*)d_in[20];

  // Workspace map (audited, no overlaps):
  char* ws = (char*)d_ws;
  int*   g      = (int*)  (ws + 0);           // [0,       16384)
  int*   row_of = (int*)  (ws + 16384);       // [16384,   32768)
  float* net    = (float*)(ws + 32768);       // [32768,   49152)
  float* prio   = (float*)(ws + 49152);       // [49152,   65536)
  float* w1d_c  = (float*)(ws + 65536);       // [65536,   66048)
  float* bzc    = (float*)(ws + 66048);       // [66048,   66560)
  uint4* w2f    = (uint4*)(ws + 131072);      // [131072,  147456)
  float* hi     = (float*)(ws + 262144);      // [262144,  2359296)
  float* hj     = (float*)(ws + 2359296);     // [2359296, 4456448)
  float* fl_c   = (float*)(ws + 4456448);     // [4456448, 4980736)
  float* ef_c   = (float*)(ws + 4980736);     // [4980736, 5505024)

  float* sharing = (float*)d_out;
  float* effm    = sharing + (long)NB*NB;
  float* total   = effm + (long)NB*NB;
  float* esent   = total + 1;
  float* erecv   = esent + NB;
  float* nafter  = erecv + NB;

  hipLaunchKernelGGL(k_hijprio, dim3(530), dim3(256), 0, stream,
                     emb, gen, cons, fp_w1, fp_b1, fp_w2, ps_w1, ps_b1, ps_w2, ps_b2,
                     assign, hourp, hi, hj, net, prio, g, row_of, w1d_c, bzc, w2f, total);
  hipLaunchKernelGGL(k_pfgreedy, dim3(128), dim3(256), 0, stream,
                     hi, hj, pos, net, prio, w1d_c, bzc, w2f, fp_b2, fp_w3, fp_b3,
                     en_w1, en_b1, en_w2, en_b2, g,
                     fl_c, ef_c, total, esent, erecv, nafter);
  hipLaunchKernelGGL(k_write, dim3(4096), dim3(256), 0, stream,
                     fl_c, ef_c, g, row_of, sharing, effm);
}